// Round 13
// baseline (162.012 us; speedup 1.0000x reference)
//
#include <hip/hip_runtime.h>
#include <hip/hip_bf16.h>

#define N_ROWS 8192
#define DIM 128   // elems per row; 256 B = 16 chunks of 16 B
#define WI 32     // i-rows per wave (2 MFMA A-tiles)
#define IBLK 128  // i-rows per block (4 waves x WI)
#define BJ 64     // j-rows staged per LDS buffer

// exp(sim/tau) == exp2(sim * SC); features pre-scaled by sqrt(SC) so the
// MFMA output IS the exp2 argument.
#define SQRT_SC 4.539816f
#define LN2F 0.6931471805599453f

typedef __attribute__((ext_vector_type(8))) short bf16x8;
typedef __attribute__((ext_vector_type(4))) float f32x4;
typedef __attribute__((address_space(3))) unsigned int as3_u32;
typedef const __attribute__((address_space(1))) unsigned int as1_u32;

// ---------------- normalize: fp32 feats -> (sqrt(SC) * L2-normalized) bf16 --
__global__ __launch_bounds__(256) void normalize_kernel(
    const float* __restrict__ feats, __hip_bfloat16* __restrict__ nf) {
  int wid = threadIdx.x >> 6;
  int lane = threadIdx.x & 63;
  int row = blockIdx.x * 4 + wid;
  const float* rp = feats + (size_t)row * DIM;
  float2 v = *reinterpret_cast<const float2*>(rp + lane * 2);
  float ss = v.x * v.x + v.y * v.y;
  #pragma unroll
  for (int m = 1; m < 64; m <<= 1) ss += __shfl_xor(ss, m, 64);
  float scale = SQRT_SC / fmaxf(sqrtf(ss), 1e-8f);
  __hip_bfloat162 h2;
  h2.x = __float2bfloat16(v.x * scale);
  h2.y = __float2bfloat16(v.y * scale);
  *reinterpret_cast<__hip_bfloat162*>(nf + (size_t)row * DIM + lane * 2) = h2;
}

// ---------------- fused similarity + exp reductions ----------------
// grid (N_ROWS/IBLK, jsplit), 4 waves/block, each wave owns WI=32 i-rows
// (2 MFMA A-tiles in registers). B staged per-block into LDS (BJ rows,
// double-buffered) with a 16B-chunk XOR swizzle: stored chunk = gc ^ (row&15),
// applied on BOTH the global source (pre-swizzle) and the ds_read address.
// Occupancy target: 32KB LDS -> 5 blocks/CU; grid 2048 blocks = 8/CU asked.
__global__ __launch_bounds__(256, 4) void supcon_main(
    const __hip_bfloat16* __restrict__ nf, const int* __restrict__ labels,
    float* __restrict__ denomP, float* __restrict__ numerP, int jrange) {
  __shared__ ushort Bs[2][BJ * DIM];  // 2 x 16 KiB
  const ushort* F = reinterpret_cast<const ushort*>(nf);
  const int lane = threadIdx.x & 63;
  const int wid = threadIdx.x >> 6;
  const int col = lane & 15;  // MFMA col (j) / A row (i)
  const int kg = lane >> 4;   // k-group
  const int wibase = blockIdx.x * IBLK + wid * WI;
  const int jbase = blockIdx.y * jrange;

  // A fragments (registers for the whole sweep) + this lane's D-row labels.
  bf16x8 a[2][4];
  int labi[2][4];
  #pragma unroll
  for (int it = 0; it < 2; ++it) {
    const ushort* ap = F + (size_t)(wibase + it * 16 + col) * DIM + kg * 8;
    #pragma unroll
    for (int c = 0; c < 4; ++c)
      a[it][c] = *reinterpret_cast<const bf16x8*>(ap + c * 32);
    #pragma unroll
    for (int r = 0; r < 4; ++r)
      labi[it][r] = labels[wibase + it * 16 + kg * 4 + r];
  }
  float denom[2][4] = {}, numer[2][4] = {};

  // staging: per instr i, this lane writes LDS row (wid*16+i*4+(lane>>4)),
  // stored chunk (lane&15); it must FETCH global chunk gc = sc ^ (row&15).
  const int srow = lane >> 4;
  const int schunk = lane & 15;

  const int nst = jrange / BJ;

#define STAGE(BUFI, JB)                                                        \
  {                                                                            \
    _Pragma("unroll") for (int i = 0; i < 4; ++i) {                            \
      int r = wid * 16 + i * 4 + srow;                                         \
      int gc = schunk ^ (r & 15);                                              \
      const ushort* gp = F + (((size_t)((JB) + r)) << 7) + (gc << 3);          \
      __builtin_amdgcn_global_load_lds(                                        \
          (as1_u32*)gp, (as3_u32*)(&Bs[BUFI][(wid * 16 + i * 4) * DIM]), 16,   \
          0, 0);                                                               \
    }                                                                          \
  }

  STAGE(0, jbase)
  __syncthreads();

  for (int t = 0; t < nst; ++t) {
    const int cur = t & 1;
    const int jb0 = jbase + t * BJ;
    if (t + 1 < nst) STAGE(cur ^ 1, jb0 + BJ)

    // this stage's j-labels (16 per subtile, lane=col)
    int labj[4];
    #pragma unroll
    for (int sub = 0; sub < 4; ++sub) labj[sub] = labels[jb0 + sub * 16 + col];

    #pragma unroll
    for (int sub = 0; sub < 4; ++sub) {
      const int jb = jb0 + sub * 16;
      const ushort* bs = &Bs[cur][sub * 16 * DIM];
      bf16x8 b[4];
      #pragma unroll
      for (int c = 0; c < 4; ++c) {
        int sc = (c * 4 + kg) ^ col;  // swizzled chunk on the read side
        b[c] = *reinterpret_cast<const bf16x8*>(bs + col * DIM + sc * 8);
      }
      f32x4 d[2];
      #pragma unroll
      for (int it = 0; it < 2; ++it) {
        f32x4 acc = {0.f, 0.f, 0.f, 0.f};
        #pragma unroll
        for (int c = 0; c < 4; ++c)
          acc = __builtin_amdgcn_mfma_f32_16x16x32_bf16(a[it][c], b[c], acc,
                                                        0, 0, 0);
        d[it] = acc;
      }
      if (jb < wibase + WI && jb + 16 > wibase) {
        // rare: tile touches the diagonal -> zero self-similarity exp
        int gj = jb + col;
        #pragma unroll
        for (int it = 0; it < 2; ++it)
          #pragma unroll
          for (int r = 0; r < 4; ++r) {
            float e = __builtin_amdgcn_exp2f(d[it][r]);
            if (wibase + it * 16 + kg * 4 + r == gj) e = 0.f;
            denom[it][r] += e;
            numer[it][r] += (labi[it][r] == labj[sub]) ? e : 0.f;
          }
      } else {
        #pragma unroll
        for (int it = 0; it < 2; ++it)
          #pragma unroll
          for (int r = 0; r < 4; ++r) {
            float e = __builtin_amdgcn_exp2f(d[it][r]);
            denom[it][r] += e;
            numer[it][r] += (labi[it][r] == labj[sub]) ? e : 0.f;
          }
      }
    }
    __syncthreads();
  }
#undef STAGE

  // reduce across the 16 j-columns (lane bits 0..3)
  #pragma unroll
  for (int m = 1; m < 16; m <<= 1)
    #pragma unroll
    for (int it = 0; it < 2; ++it)
      #pragma unroll
      for (int r = 0; r < 4; ++r) {
        denom[it][r] += __shfl_xor(denom[it][r], m, 64);
        numer[it][r] += __shfl_xor(numer[it][r], m, 64);
      }
  if (col == 0) {
    size_t s = blockIdx.y;
    #pragma unroll
    for (int it = 0; it < 2; ++it)
      #pragma unroll
      for (int r = 0; r < 4; ++r) {
        size_t idx = s * N_ROWS + (wibase + it * 16 + kg * 4 + r);
        denomP[idx] = denom[it][r];
        numerP[idx] = numer[it][r];
      }
  }
}

// ---------------- finalize 1: per-row loss, block partials ----------------
// 32 blocks; positive count per row = hist[label]-1 via a 512-bin LDS
// histogram, so the GEMM loop never tracks counts.
__global__ __launch_bounds__(256) void finalize1(
    const float* __restrict__ denomP, const float* __restrict__ numerP,
    const int* __restrict__ labels, float* __restrict__ blkP, int jsplit) {
  __shared__ int hist[512];
  int tid = threadIdx.x;
  for (int i = tid; i < 512; i += 256) hist[i] = 0;
  __syncthreads();
  for (int i = tid; i < N_ROWS; i += 256) atomicAdd(&hist[labels[i]], 1);
  __syncthreads();

  int row = blockIdx.x * 256 + tid;
  float den = 0.f, num = 0.f;
  for (int s = 0; s < jsplit; ++s) {
    den += denomP[(size_t)s * N_ROWS + row];
    num += numerP[(size_t)s * N_ROWS + row];
  }
  bool valid = (hist[labels[row]] - 1) > 0;
  float loss = LN2F * (__builtin_amdgcn_logf(fmaxf(den, 1e-8f)) -
                       __builtin_amdgcn_logf(num + 1e-12f));
  float ls = valid ? loss : 0.f;
  float lc = valid ? 1.f : 0.f;
  #pragma unroll
  for (int m = 1; m < 64; m <<= 1) {
    ls += __shfl_xor(ls, m, 64);
    lc += __shfl_xor(lc, m, 64);
  }
  __shared__ float ss[4], sc2[4];
  int wid = tid >> 6, lane = tid & 63;
  if (lane == 0) { ss[wid] = ls; sc2[wid] = lc; }
  __syncthreads();
  if (tid == 0) {
    blkP[blockIdx.x * 2] = ss[0] + ss[1] + ss[2] + ss[3];
    blkP[blockIdx.x * 2 + 1] = sc2[0] + sc2[1] + sc2[2] + sc2[3];
  }
}

// ---------------- finalize 2: combine 32 block partials ----------------
__global__ __launch_bounds__(64) void finalize2(const float* __restrict__ blkP,
                                                float* __restrict__ out) {
  int lane = threadIdx.x;
  float s = (lane < 32) ? blkP[lane * 2] : 0.f;
  float c = (lane < 32) ? blkP[lane * 2 + 1] : 0.f;
  #pragma unroll
  for (int m = 1; m < 64; m <<= 1) {
    s += __shfl_xor(s, m, 64);
    c += __shfl_xor(c, m, 64);
  }
  if (lane == 0) out[0] = (c > 0.f) ? s / c : 0.f;
}

extern "C" void kernel_launch(void* const* d_in, const int* in_sizes, int n_in,
                              void* d_out, int out_size, void* d_ws,
                              size_t ws_size, hipStream_t stream) {
  const float* feats = (const float*)d_in[0];
  const int* labels = (const int*)d_in[1];
  float* out = (float*)d_out;

  // ws layout: nf (2MB bf16) | denomP | numerP | blkP (64 floats)
  __hip_bfloat16* nf = (__hip_bfloat16*)d_ws;
  size_t nf_bytes = (size_t)N_ROWS * DIM * sizeof(__hip_bfloat16);

  int jsplit = 32;
  while (jsplit > 1 &&
         ws_size < nf_bytes + ((size_t)jsplit * N_ROWS * 2 + 64) * sizeof(float))
    jsplit >>= 1;
  int jrange = N_ROWS / jsplit;

  float* denomP = (float*)((char*)d_ws + nf_bytes);
  float* numerP = denomP + (size_t)jsplit * N_ROWS;
  float* blkP = numerP + (size_t)jsplit * N_ROWS;

  normalize_kernel<<<N_ROWS / 4, 256, 0, stream>>>(feats, nf);
  supcon_main<<<dim3(N_ROWS / IBLK, jsplit), 256, 0, stream>>>(
      nf, labels, denomP, numerP, jrange);
  finalize1<<<32, 256, 0, stream>>>(denomP, numerP, labels, blkP, jsplit);
  finalize2<<<1, 64, 0, stream>>>(blkP, out);
}

// Round 15
// 108.744 us; speedup vs baseline: 1.4898x; 1.4898x over previous
//
#include <hip/hip_runtime.h>
#include <hip/hip_bf16.h>

#define N_ROWS 8192
#define DIM 128   // elems per row; 256 B = 16 chunks of 16 B
#define WI 32     // i-rows per wave (2 MFMA A-tiles)
#define IBLK 128  // i-rows per block (4 waves x WI)
#define BJ 64     // j-rows staged per LDS buffer

// exp(sim/tau) == exp2(sim * SC); features pre-scaled by sqrt(SC) so the
// MFMA output IS the exp2 argument.
#define SQRT_SC 4.539816f
#define LN2F 0.6931471805599453f

typedef __attribute__((ext_vector_type(8))) short bf16x8;
typedef __attribute__((ext_vector_type(4))) float f32x4;
typedef __attribute__((address_space(3))) unsigned int as3_u32;
typedef const __attribute__((address_space(1))) unsigned int as1_u32;

// ---------------- normalize: fp32 feats -> (sqrt(SC) * L2-normalized) bf16 --
__global__ __launch_bounds__(256) void normalize_kernel(
    const float* __restrict__ feats, __hip_bfloat16* __restrict__ nf) {
  int wid = threadIdx.x >> 6;
  int lane = threadIdx.x & 63;
  int row = blockIdx.x * 4 + wid;
  const float* rp = feats + (size_t)row * DIM;
  float2 v = *reinterpret_cast<const float2*>(rp + lane * 2);
  float ss = v.x * v.x + v.y * v.y;
  #pragma unroll
  for (int m = 1; m < 64; m <<= 1) ss += __shfl_xor(ss, m, 64);
  float scale = SQRT_SC / fmaxf(sqrtf(ss), 1e-8f);
  __hip_bfloat162 h2;
  h2.x = __float2bfloat16(v.x * scale);
  h2.y = __float2bfloat16(v.y * scale);
  *reinterpret_cast<__hip_bfloat162*>(nf + (size_t)row * DIM + lane * 2) = h2;
}

// ---------------- fused similarity + exp reductions ----------------
// grid (N_ROWS/IBLK, jsplit), 4 waves/block, each wave owns WI=32 i-rows
// (2 MFMA A-tiles in registers). B staged per-block into LDS (BJ rows,
// double-buffered) with a 16B-chunk XOR swizzle: stored chunk = gc ^ (row&15),
// applied on BOTH the global source (pre-swizzle) and the ds_read address.
// launch_bounds(256,2): VGPR cap 128 >= ~105 demand -> NO SPILLS (round-13
// lesson: (256,4) capped VGPR at 64 and spilled ~40 regs -> 102 MB scratch
// writes/dispatch). LDS 32KB -> 5 blocks/CU; VGPR<=128 -> 4 waves/SIMD.
__global__ __launch_bounds__(256, 2) void supcon_main(
    const __hip_bfloat16* __restrict__ nf, const int* __restrict__ labels,
    float* __restrict__ denomP, float* __restrict__ numerP, int jrange) {
  __shared__ ushort Bs[2][BJ * DIM];  // 2 x 16 KiB
  const ushort* F = reinterpret_cast<const ushort*>(nf);
  const int lane = threadIdx.x & 63;
  const int wid = threadIdx.x >> 6;
  const int col = lane & 15;  // MFMA col (j) / A row (i)
  const int kg = lane >> 4;   // k-group
  const int wibase = blockIdx.x * IBLK + wid * WI;
  const int jbase = blockIdx.y * jrange;

  // A fragments (registers for the whole sweep) + this lane's D-row labels.
  bf16x8 a[2][4];
  int labi[2][4];
  #pragma unroll
  for (int it = 0; it < 2; ++it) {
    const ushort* ap = F + (size_t)(wibase + it * 16 + col) * DIM + kg * 8;
    #pragma unroll
    for (int c = 0; c < 4; ++c)
      a[it][c] = *reinterpret_cast<const bf16x8*>(ap + c * 32);
    #pragma unroll
    for (int r = 0; r < 4; ++r)
      labi[it][r] = labels[wibase + it * 16 + kg * 4 + r];
  }
  float denom[2][4] = {}, numer[2][4] = {};

  // staging: per instr i, this lane writes LDS row (wid*16+i*4+(lane>>4)),
  // stored chunk (lane&15); it must FETCH global chunk gc = sc ^ (row&15).
  const int srow = lane >> 4;
  const int schunk = lane & 15;

  const int nst = jrange / BJ;

#define STAGE(BUFI, JB)                                                        \
  {                                                                            \
    _Pragma("unroll") for (int i = 0; i < 4; ++i) {                            \
      int r = wid * 16 + i * 4 + srow;                                         \
      int gc = schunk ^ (r & 15);                                              \
      const ushort* gp = F + (((size_t)((JB) + r)) << 7) + (gc << 3);          \
      __builtin_amdgcn_global_load_lds(                                        \
          (as1_u32*)gp, (as3_u32*)(&Bs[BUFI][(wid * 16 + i * 4) * DIM]), 16,   \
          0, 0);                                                               \
    }                                                                          \
  }

  STAGE(0, jbase)
  __syncthreads();

  for (int t = 0; t < nst; ++t) {
    const int cur = t & 1;
    const int jb0 = jbase + t * BJ;
    if (t + 1 < nst) STAGE(cur ^ 1, jb0 + BJ)

    // this stage's j-labels (16 per subtile, lane=col)
    int labj[4];
    #pragma unroll
    for (int sub = 0; sub < 4; ++sub) labj[sub] = labels[jb0 + sub * 16 + col];

    #pragma unroll
    for (int sub = 0; sub < 4; ++sub) {
      const int jb = jb0 + sub * 16;
      const ushort* bs = &Bs[cur][sub * 16 * DIM];
      bf16x8 b[4];
      #pragma unroll
      for (int c = 0; c < 4; ++c) {
        int sc = (c * 4 + kg) ^ col;  // swizzled chunk on the read side
        b[c] = *reinterpret_cast<const bf16x8*>(bs + col * DIM + sc * 8);
      }
      f32x4 d[2];
      #pragma unroll
      for (int it = 0; it < 2; ++it) {
        f32x4 acc = {0.f, 0.f, 0.f, 0.f};
        #pragma unroll
        for (int c = 0; c < 4; ++c)
          acc = __builtin_amdgcn_mfma_f32_16x16x32_bf16(a[it][c], b[c], acc,
                                                        0, 0, 0);
        d[it] = acc;
      }
      if (jb < wibase + WI && jb + 16 > wibase) {
        // rare: tile touches the diagonal -> zero self-similarity exp
        int gj = jb + col;
        #pragma unroll
        for (int it = 0; it < 2; ++it)
          #pragma unroll
          for (int r = 0; r < 4; ++r) {
            float e = __builtin_amdgcn_exp2f(d[it][r]);
            if (wibase + it * 16 + kg * 4 + r == gj) e = 0.f;
            denom[it][r] += e;
            numer[it][r] += (labi[it][r] == labj[sub]) ? e : 0.f;
          }
      } else {
        #pragma unroll
        for (int it = 0; it < 2; ++it)
          #pragma unroll
          for (int r = 0; r < 4; ++r) {
            float e = __builtin_amdgcn_exp2f(d[it][r]);
            denom[it][r] += e;
            numer[it][r] += (labi[it][r] == labj[sub]) ? e : 0.f;
          }
      }
    }
    __syncthreads();
  }
#undef STAGE

  // reduce across the 16 j-columns (lane bits 0..3)
  #pragma unroll
  for (int m = 1; m < 16; m <<= 1)
    #pragma unroll
    for (int it = 0; it < 2; ++it)
      #pragma unroll
      for (int r = 0; r < 4; ++r) {
        denom[it][r] += __shfl_xor(denom[it][r], m, 64);
        numer[it][r] += __shfl_xor(numer[it][r], m, 64);
      }
  if (col == 0) {
    size_t s = blockIdx.y;
    #pragma unroll
    for (int it = 0; it < 2; ++it)
      #pragma unroll
      for (int r = 0; r < 4; ++r) {
        size_t idx = s * N_ROWS + (wibase + it * 16 + kg * 4 + r);
        denomP[idx] = denom[it][r];
        numerP[idx] = numer[it][r];
      }
  }
}

// ---------------- finalize 1: per-row loss, block partials ----------------
// 32 blocks; positive count per row = hist[label]-1 via a 512-bin LDS
// histogram, so the GEMM loop never tracks counts.
__global__ __launch_bounds__(256) void finalize1(
    const float* __restrict__ denomP, const float* __restrict__ numerP,
    const int* __restrict__ labels, float* __restrict__ blkP, int jsplit) {
  __shared__ int hist[512];
  int tid = threadIdx.x;
  for (int i = tid; i < 512; i += 256) hist[i] = 0;
  __syncthreads();
  for (int i = tid; i < N_ROWS; i += 256) atomicAdd(&hist[labels[i]], 1);
  __syncthreads();

  int row = blockIdx.x * 256 + tid;
  float den = 0.f, num = 0.f;
  for (int s = 0; s < jsplit; ++s) {
    den += denomP[(size_t)s * N_ROWS + row];
    num += numerP[(size_t)s * N_ROWS + row];
  }
  bool valid = (hist[labels[row]] - 1) > 0;
  float loss = LN2F * (__builtin_amdgcn_logf(fmaxf(den, 1e-8f)) -
                       __builtin_amdgcn_logf(num + 1e-12f));
  float ls = valid ? loss : 0.f;
  float lc = valid ? 1.f : 0.f;
  #pragma unroll
  for (int m = 1; m < 64; m <<= 1) {
    ls += __shfl_xor(ls, m, 64);
    lc += __shfl_xor(lc, m, 64);
  }
  __shared__ float ss[4], sc2[4];
  int wid = tid >> 6, lane = tid & 63;
  if (lane == 0) { ss[wid] = ls; sc2[wid] = lc; }
  __syncthreads();
  if (tid == 0) {
    blkP[blockIdx.x * 2] = ss[0] + ss[1] + ss[2] + ss[3];
    blkP[blockIdx.x * 2 + 1] = sc2[0] + sc2[1] + sc2[2] + sc2[3];
  }
}

// ---------------- finalize 2: combine 32 block partials ----------------
__global__ __launch_bounds__(64) void finalize2(const float* __restrict__ blkP,
                                                float* __restrict__ out) {
  int lane = threadIdx.x;
  float s = (lane < 32) ? blkP[lane * 2] : 0.f;
  float c = (lane < 32) ? blkP[lane * 2 + 1] : 0.f;
  #pragma unroll
  for (int m = 1; m < 64; m <<= 1) {
    s += __shfl_xor(s, m, 64);
    c += __shfl_xor(c, m, 64);
  }
  if (lane == 0) out[0] = (c > 0.f) ? s / c : 0.f;
}

extern "C" void kernel_launch(void* const* d_in, const int* in_sizes, int n_in,
                              void* d_out, int out_size, void* d_ws,
                              size_t ws_size, hipStream_t stream) {
  const float* feats = (const float*)d_in[0];
  const int* labels = (const int*)d_in[1];
  float* out = (float*)d_out;

  // ws layout: nf (2MB bf16) | denomP | numerP | blkP (64 floats)
  __hip_bfloat16* nf = (__hip_bfloat16*)d_ws;
  size_t nf_bytes = (size_t)N_ROWS * DIM * sizeof(__hip_bfloat16);

  int jsplit = 32;
  while (jsplit > 1 &&
         ws_size < nf_bytes + ((size_t)jsplit * N_ROWS * 2 + 64) * sizeof(float))
    jsplit >>= 1;
  int jrange = N_ROWS / jsplit;

  float* denomP = (float*)((char*)d_ws + nf_bytes);
  float* numerP = denomP + (size_t)jsplit * N_ROWS;
  float* blkP = numerP + (size_t)jsplit * N_ROWS;

  normalize_kernel<<<N_ROWS / 4, 256, 0, stream>>>(feats, nf);
  supcon_main<<<dim3(N_ROWS / IBLK, jsplit), 256, 0, stream>>>(
      nf, labels, denomP, numerP, jrange);
  finalize1<<<32, 256, 0, stream>>>(denomP, numerP, labels, blkP, jsplit);
  finalize2<<<1, 64, 0, stream>>>(blkP, out);
}